// Round 4
// baseline (183.850 us; speedup 1.0000x reference)
//
#include <hip/hip_runtime.h>

// HSI_RWKV fused block kernel, MI355X (gfx950), R12.
// out = block(x) + T(block(T(x))) == 2 * block_per_token(x)  (block is per-token).
// R12 = R11's PROVEN structure (dbuf WldsA/WldsB, padded LDA/LDW, register
// staging, linear cvt_all, identical barrier skeleton) + exactly ONE change:
//   TWO 64-token sets per block (128 tokens, grid 1024 -> 512). Each phase
//   stages its weight tile once and runs the gemm for BOTH sets, with
//   B-fragments loaded from LDS once and reused (gemm16x2): per-phase MFMA
//   doubles while weight ds_reads stay constant; per-token staging/barrier
//   cost halves. Set1 is a disjoint replica of set0 (own act/wht LDS slices,
//   own t/acc/akv registers) -- per-wave semantics unchanged from R11.
// Rationale: R11 counters (MfmaUtil 10.2, VALUBusy 28, HBM 7, Occ 11) =>
// still phase-overhead-bound: ~4.7K cy/phase vs ~2.2K cy of work; staging +
// barrier cost was paid per 64 tokens. LDS 103424 -> 137216 B (1 block/CU);
// __launch_bounds__(256,1) so ~230 VGPR allocs without spill (occupancy is
// LDS-capped anyway).
// MFMA layouts (m89/m91): A m=lane&15,k=q*8+j; B n=lane&15,k=q*8+j;
// D row(token)=q*4+reg, col(out-ch)=lane&15. Frags: short8 bit patterns.

#define HW    16384
#define CDIM  128
#define LDA   132     // act/wht row stride (ushorts); 264 B, 8B-aligned
#define LDW   136     // weight tile row stride (ushorts); 272 B -> ~2-way banks
#define TPW   16      // tokens per wave per set
#define NW    4

#define OFF_OUT 0
#define OFF_WHT 16384
#define OFF_KEY 32768
#define OFF_REC 98304
#define OFF_VAL 114688
#define WS_ELEMS 180224   // *2 bytes

typedef __attribute__((ext_vector_type(8))) short short8;  // 8 bf16 bit patterns
typedef __attribute__((ext_vector_type(4))) float f32x4;

__device__ __forceinline__ float bf2f(ushort h) {
    union { uint u; float f; } v; v.u = ((uint)h) << 16; return v.f;
}
__device__ __forceinline__ ushort f2bf(float f) {
    union { float f; uint u; } v; v.f = f;
    uint u = v.u + 0x7fffu + ((v.u >> 16) & 1u);   // RNE
    return (ushort)(u >> 16);
}
__device__ __forceinline__ float sigm(float x) {
    return 1.f / (1.f + __expf(-x));
}

// one-launch weight conversion: 180224 elements, grid 704 x 256 (R7+-proven)
__global__ void cvt_all(const float* __restrict__ Wout, const float* __restrict__ Wwht,
                        const float* __restrict__ Wkey, const float* __restrict__ Wrec,
                        const float* __restrict__ Wval, ushort* __restrict__ ws) {
    int i = blockIdx.x * 256 + threadIdx.x;
    float v;
    if      (i < 32768)  v = (i < 16384) ? Wout[i] : Wwht[i - 16384];
    else if (i < 98304)  v = Wkey[i - 32768];
    else if (i < 114688) v = Wrec[i - 98304];
    else                 v = Wval[i - 114688];
    ws[i] = f2bf(v);
}

// Stage a 128x128 bf16 tile W[row0..row0+128)[k0..k0+128) into Wl (LDW-padded).
// 256 threads x 16B x 8 iters = 32 KB; batched independent loads (R8-proven).
template<bool PRE>
__device__ __forceinline__ void stageW(ushort* Wl,
                                       const ushort* __restrict__ wsrc,
                                       const float* __restrict__ fsrc,
                                       int src_ld, int row0, int k0, int tid) {
    const int rr = tid >> 4, cc = (tid & 15) * 8;
#pragma unroll
    for (int j = 0; j < 8; ++j) {
        const int r  = j * 16 + rr;
        const int si = (row0 + r) * src_ld + k0 + cc;
        if (PRE) {
            *(short8*)&Wl[r * LDW + cc] = *(const short8*)&wsrc[si];
        } else {
            const float* p = fsrc + si;
            float4 f0 = *(const float4*)p;
            float4 f1 = *(const float4*)(p + 4);
            union { ushort u[8]; short8 s; } t;
            t.u[0]=f2bf(f0.x); t.u[1]=f2bf(f0.y); t.u[2]=f2bf(f0.z); t.u[3]=f2bf(f0.w);
            t.u[4]=f2bf(f1.x); t.u[5]=f2bf(f1.y); t.u[6]=f2bf(f1.z); t.u[7]=f2bf(f1.w);
            *(short8*)&Wl[r * LDW + cc] = t.s;
        }
    }
}

__device__ __forceinline__ short8 ldA8(const ushort* p) {   // 8B-aligned LDS
    union { uint2 x[2]; short8 s; } r;
    r.x[0] = *(const uint2*)p;
    r.x[1] = *(const uint2*)(p + 4);
    return r.s;
}

// accX[nt] += AX(16 tok x K=128, wave-local LDS) @ Wl(128x128 LDS tile)^T for
// both token sets, with B-fragments loaded ONCE and reused (amortization core).
__device__ __forceinline__ void gemm16x2(const ushort* A0, const ushort* A1,
                                         const ushort* Wl, int q, int c,
                                         f32x4 acc0[8], f32x4 acc1[8]) {
#pragma unroll
    for (int kk = 0; kk < 4; ++kk) {
        short8 b[8];
#pragma unroll
        for (int nt = 0; nt < 8; ++nt)
            b[nt] = *(const short8*)&Wl[(nt * 16 + c) * LDW + kk * 32 + q * 8];
        short8 a0 = ldA8(A0 + c * LDA + kk * 32 + q * 8);
        short8 a1 = ldA8(A1 + c * LDA + kk * 32 + q * 8);
#pragma unroll
        for (int nt = 0; nt < 8; ++nt) {
            acc0[nt] = __builtin_amdgcn_mfma_f32_16x16x32_bf16(a0, b[nt], acc0[nt], 0, 0, 0);
            acc1[nt] = __builtin_amdgcn_mfma_f32_16x16x32_bf16(a1, b[nt], acc1[nt], 0, 0, 0);
        }
    }
}

__device__ __forceinline__ void zero8(f32x4 a[8]) {
#pragma unroll
    for (int nt = 0; nt < 8; ++nt) a[nt] = (f32x4){0.f, 0.f, 0.f, 0.f};
}

// D-fragment (token-major) store: row(token)=q*4+r, col=nt*16+c
__device__ __forceinline__ void storeD(ushort* dst, const f32x4 acc[8], int q, int c) {
#pragma unroll
    for (int nt = 0; nt < 8; ++nt)
#pragma unroll
        for (int r = 0; r < 4; ++r)
            dst[(q * 4 + r) * LDA + nt * 16 + c] = f2bf(acc[nt][r]);
}
// relu^2 variant
__device__ __forceinline__ void storeK(ushort* dst, const f32x4 acc[8], int q, int c) {
#pragma unroll
    for (int nt = 0; nt < 8; ++nt)
#pragma unroll
        for (int r = 0; r < 4; ++r) {
            float v = fmaxf(acc[nt][r], 0.f);
            dst[(q * 4 + r) * LDA + nt * 16 + c] = f2bf(v * v);
        }
}
// sigmoid(acc)*akv variant
__device__ __forceinline__ void storeP(ushort* dst, const f32x4 acc[8],
                                       const f32x4 akv[8], int q, int c) {
#pragma unroll
    for (int nt = 0; nt < 8; ++nt)
#pragma unroll
        for (int r = 0; r < 4; ++r)
            dst[(q * 4 + r) * LDA + nt * 16 + c] =
                f2bf(sigm(acc[nt][r]) * akv[nt][r]);
}

// per-token LN stats (R5-proven): token = lane&15, partials across 4 quads
__device__ __forceinline__ void ln_stats(const float* t, float& mu, float& rs) {
    float s1 = 0.f, s2 = 0.f;
#pragma unroll
    for (int i = 0; i < 32; ++i) { s1 += t[i]; s2 += t[i] * t[i]; }
    s1 += __shfl_xor(s1, 16); s2 += __shfl_xor(s2, 16);
    s1 += __shfl_xor(s1, 32); s2 += __shfl_xor(s2, 32);
    mu = s1 * (1.f / 128.f);
    rs = rsqrtf(s2 * (1.f / 128.f) - mu * mu + 1e-5f);
}

// LN + optional silu + bf16-pack into a wave-local LDS row (token = c)
template<bool SILU>
__device__ __forceinline__ void ln_pack(const float* t, const float* __restrict__ G,
                                        const float* __restrict__ B,
                                        ushort* dst, int q, int c) {
    float mu, rs;
    ln_stats(t, mu, rs);
#pragma unroll
    for (int j = 0; j < 16; ++j) {
        int ch = 32 * q + 2 * j;
        float y0 = (t[2*j]   - mu) * rs * G[ch]   + B[ch];
        float y1 = (t[2*j+1] - mu) * rs * G[ch+1] + B[ch+1];
        if (SILU) { y0 *= sigm(y0); y1 *= sigm(y1); }
        *(uint*)&dst[c * LDA + ch] = (uint)f2bf(y0) | ((uint)f2bf(y1) << 16);
    }
}

template<bool PRE>
__global__ __launch_bounds__(256, 1) void rwkv_mfma(
    const float* __restrict__ X,
    const float* __restrict__ G0, const float* __restrict__ B0,
    const float* __restrict__ G1, const float* __restrict__ B1,
    const float* __restrict__ G2, const float* __restrict__ B2,
    const float* __restrict__ WoutF, const float* __restrict__ WwhtF,
    const float* __restrict__ WkeyF, const float* __restrict__ WrecF,
    const float* __restrict__ WvalF,
    const ushort* __restrict__ Wb,
    float* __restrict__ Y)
{
    __shared__ __align__(16) ushort act0S[NW * TPW * LDA];  // 16896 B each
    __shared__ __align__(16) ushort act1S[NW * TPW * LDA];
    __shared__ __align__(16) ushort wht0S[NW * TPW * LDA];
    __shared__ __align__(16) ushort wht1S[NW * TPW * LDA];
    __shared__ __align__(16) ushort WldsA[128 * LDW];       // 34816 B: OUT,KEY*,REC
    __shared__ __align__(16) ushort WldsB[128 * LDW];       // 34816 B: WHT,VAL*
    // total 137216 B -> 1 block/CU

    const int tid = threadIdx.x;
    const int w = tid >> 6, l = tid & 63;
    const int q = l >> 4, c = l & 15;
    ushort* act0 = act0S + w * (TPW * LDA);
    ushort* act1 = act1S + w * (TPW * LDA);
    ushort* wht0 = wht0S + w * (TPW * LDA);
    ushort* wht1 = wht1S + w * (TPW * LDA);

    const int s128 = blockIdx.x * 128;         // 128 tokens per block (2 sets)
    const int bb  = s128 >> 14;
    const int s0  = s128 & (HW - 1);           // 16384/128=128 blocks/batch: no crossing
    const long gb0 = (long)(bb * CDIM) * HW + s0 + 16 * w + c;
    const long gb1 = gb0 + 64;

    // ==== P0: stage OUT -> A (overlaps X loads + LN0/LN1, both sets) ====
    stageW<PRE>(WldsA, Wb + OFF_OUT, WoutF, 128, 0, 0, tid);

    float t0[32], t1[32];
#pragma unroll
    for (int i = 0; i < 32; ++i) t0[i] = X[gb0 + (long)(32 * q + i) * HW];
#pragma unroll
    for (int i = 0; i < 32; ++i) t1[i] = X[gb1 + (long)(32 * q + i) * HW];

    {   // LN0 both sets
        float mu, rs;
        ln_stats(t0, mu, rs);
#pragma unroll
        for (int i = 0; i < 32; ++i) {
            int ch = 32 * q + i;
            t0[i] = (t0[i] - mu) * rs * G0[ch] + B0[ch];
        }
        ln_stats(t1, mu, rs);
#pragma unroll
        for (int i = 0; i < 32; ++i) {
            int ch = 32 * q + i;
            t1[i] = (t1[i] - mu) * rs * G0[ch] + B0[ch];
        }
    }
    ln_pack<true>(t0, G1, B1, act0, q, c);     // LN1 + silu -> a1
    ln_pack<true>(t1, G1, B1, act1, q, c);
    __syncthreads();                           // OUT staged, a1 visible

    // ==== P1: att = a1 @ W_out^T (A); stage WHT -> B ====
    stageW<PRE>(WldsB, Wb + OFF_WHT, WwhtF, 128, 0, 0, tid);
    f32x4 acc0[8], acc1[8];
    zero8(acc0); zero8(acc1);
    gemm16x2(act0, act1, WldsA, q, c, acc0, acc1);
    storeD(wht0, acc0, q, c);
    storeD(wht1, acc1, q, c);
    __syncthreads();                           // WHT staged, att visible, A free

    // ==== P2: t1r = t + att; y2 = LN2; wht = y2 @ W_whiten^T (B); KEY0 -> A ====
    stageW<PRE>(WldsA, Wb + OFF_KEY, WkeyF, 128, 0, 0, tid);
#pragma unroll
    for (int i = 0; i < 32; ++i)
        t0[i] += bf2f(wht0[c * LDA + 32 * q + i]);
#pragma unroll
    for (int i = 0; i < 32; ++i)
        t1[i] += bf2f(wht1[c * LDA + 32 * q + i]);
    ln_pack<false>(t0, G2, B2, act0, q, c);    // y2 -> act
    ln_pack<false>(t1, G2, B2, act1, q, c);
    zero8(acc0); zero8(acc1);
    gemm16x2(act0, act1, WldsB, q, c, acc0, acc1);  // in-wave: writes precede reads
    storeD(wht0, acc0, q, c);                  // overwrites att (read above, in-wave)
    storeD(wht1, acc1, q, c);
    __syncthreads();                           // KEY0 staged, wht visible, B free

    // ==== chunks: KEY_c on A (stage VAL_c -> B); VAL_c on B (stage next -> A) ====
    f32x4 akv0[8], akv1[8];
    zero8(akv0); zero8(akv1);
    for (int chunk = 0; chunk < 4; ++chunk) {
        // KEY phase: k = relu(wht @ W_key_c^T)^2
        stageW<PRE>(WldsB, Wb + OFF_VAL, WvalF, 512, 0, chunk * 128, tid);
        zero8(acc0); zero8(acc1);
        gemm16x2(wht0, wht1, WldsA, q, c, acc0, acc1);
        storeK(act0, acc0, q, c);
        storeK(act1, acc1, q, c);
        __syncthreads();                       // VAL_c staged, k visible, A free

        // VAL phase: akv += k @ W_value_c^T
        if (chunk < 3)
            stageW<PRE>(WldsA, Wb + OFF_KEY, WkeyF, 128, (chunk + 1) * 128, 0, tid);
        else
            stageW<PRE>(WldsA, Wb + OFF_REC, WrecF, 128, 0, 0, tid);
        gemm16x2(act0, act1, WldsB, q, c, akv0, akv1);
        __syncthreads();                       // next tile staged, B free
    }

    // ==== P11: r = sigmoid(wht @ W_recep^T) (A); prod = r*kv -> act ====
    zero8(acc0); zero8(acc1);
    gemm16x2(wht0, wht1, WldsA, q, c, acc0, acc1);
    storeP(act0, acc0, akv0, q, c);
    storeP(act1, acc1, akv1, q, c);
    __syncthreads();                           // prod visible

    // ==== out = 2 * (t1r + r*kv), both sets ====
#pragma unroll
    for (int i = 0; i < 32; ++i) {
        float v = t0[i] + bf2f(act0[c * LDA + 32 * q + i]);
        Y[gb0 + (long)(32 * q + i) * HW] = 2.f * v;
    }
#pragma unroll
    for (int i = 0; i < 32; ++i) {
        float v = t1[i] + bf2f(act1[c * LDA + 32 * q + i]);
        Y[gb1 + (long)(32 * q + i) * HW] = 2.f * v;
    }
}

extern "C" void kernel_launch(void* const* d_in, const int* in_sizes, int n_in,
                              void* d_out, int out_size, void* d_ws, size_t ws_size,
                              hipStream_t stream) {
    (void)in_sizes; (void)n_in; (void)out_size;
    const float* X  = (const float*)d_in[0];
    const float* G0 = (const float*)d_in[1];  const float* B0 = (const float*)d_in[2];
    const float* G1 = (const float*)d_in[3];  const float* B1 = (const float*)d_in[4];
    const float* G2 = (const float*)d_in[5];  const float* B2 = (const float*)d_in[6];
    const float* Wout = (const float*)d_in[7];
    const float* Wwht = (const float*)d_in[8];
    const float* Wkey = (const float*)d_in[9];
    const float* Wrec = (const float*)d_in[10];
    const float* Wval = (const float*)d_in[11];
    float* Y = (float*)d_out;

    const bool pre = ws_size >= (size_t)WS_ELEMS * 2;
    if (pre) {
        ushort* ws = (ushort*)d_ws;
        cvt_all<<<704, 256, 0, stream>>>(Wout, Wwht, Wkey, Wrec, Wval, ws);
        rwkv_mfma<true><<<512, 256, 0, stream>>>(
            X, G0, B0, G1, B1, G2, B2,
            Wout, Wwht, Wkey, Wrec, Wval, ws, Y);
    } else {
        rwkv_mfma<false><<<512, 256, 0, stream>>>(
            X, G0, B0, G1, B1, G2, B2,
            Wout, Wwht, Wkey, Wrec, Wval, nullptr, Y);
    }
}

// Round 5
// 159.892 us; speedup vs baseline: 1.1498x; 1.1498x over previous
//
#include <hip/hip_runtime.h>

// HSI_RWKV fused block kernel, MI355X (gfx950), R13.
// out = block(x) + T(block(T(x))) == 2 * block_per_token(x)  (block is per-token).
// R13 = R11's PROVEN per-wave program (64-token-set per-wave shape, dbuf
// WldsA/WldsB, padded LDA/LDW, register staging, linear cvt_all, identical
// barrier skeleton) + exactly ONE change:
//   8 WAVES PER BLOCK (512 threads), 128 tokens/block, grid 512. Each wave
//   still owns 16 tokens with its own act/wht LDS slice -- per-wave semantics
//   byte-identical to R11. LDS 137216 B -> 1 block/CU, but 8 waves/CU =
//   2 waves/SIMD: one wave's MFMA/VALU fills the other's ds_read/stage stalls
//   (m114: MFMA+VALU pipes co-schedule across waves).
// Rationale: R12 falsified the fixed-overhead theory (doubling per-wave work
// doubled phase time: 23.4 -> 49 us per block). R11/R12 Occupancy 11% =
// 1 wave/SIMD = zero latency hiding; dep-stall inside a lone wave is the
// missing ~65%. R12's gemm16x2 two-set-per-wave REVERTED (regressed).
// MFMA layouts (m89/m91): A m=lane&15,k=q*8+j; B n=lane&15,k=q*8+j;
// D row(token)=q*4+reg, col(out-ch)=lane&15. Frags: short8 bit patterns.

#define HW    16384
#define CDIM  128
#define LDA   132     // act/wht row stride (ushorts); 264 B, 8B-aligned
#define LDW   136     // weight tile row stride (ushorts); 272 B -> ~2-way banks
#define TPW   16      // tokens per wave
#define NW    8       // waves per block (512 threads)

#define OFF_OUT 0
#define OFF_WHT 16384
#define OFF_KEY 32768
#define OFF_REC 98304
#define OFF_VAL 114688
#define WS_ELEMS 180224   // *2 bytes

typedef __attribute__((ext_vector_type(8))) short short8;  // 8 bf16 bit patterns
typedef __attribute__((ext_vector_type(4))) float f32x4;

__device__ __forceinline__ float bf2f(ushort h) {
    union { uint u; float f; } v; v.u = ((uint)h) << 16; return v.f;
}
__device__ __forceinline__ ushort f2bf(float f) {
    union { float f; uint u; } v; v.f = f;
    uint u = v.u + 0x7fffu + ((v.u >> 16) & 1u);   // RNE
    return (ushort)(u >> 16);
}
__device__ __forceinline__ float sigm(float x) {
    return 1.f / (1.f + __expf(-x));
}

// one-launch weight conversion: 180224 elements, grid 704 x 256 (R7+-proven)
__global__ void cvt_all(const float* __restrict__ Wout, const float* __restrict__ Wwht,
                        const float* __restrict__ Wkey, const float* __restrict__ Wrec,
                        const float* __restrict__ Wval, ushort* __restrict__ ws) {
    int i = blockIdx.x * 256 + threadIdx.x;
    float v;
    if      (i < 32768)  v = (i < 16384) ? Wout[i] : Wwht[i - 16384];
    else if (i < 98304)  v = Wkey[i - 32768];
    else if (i < 114688) v = Wrec[i - 98304];
    else                 v = Wval[i - 114688];
    ws[i] = f2bf(v);
}

// Stage a 128x128 bf16 tile W[row0..row0+128)[k0..k0+128) into Wl (LDW-padded).
// 512 threads x 16B x 4 iters = 32 KB; batched independent loads.
template<bool PRE>
__device__ __forceinline__ void stageW(ushort* Wl,
                                       const ushort* __restrict__ wsrc,
                                       const float* __restrict__ fsrc,
                                       int src_ld, int row0, int k0, int tid) {
    const int rr = tid >> 4, cc = (tid & 15) * 8;   // rr in 0..31
#pragma unroll
    for (int j = 0; j < 4; ++j) {
        const int r  = j * 32 + rr;
        const int si = (row0 + r) * src_ld + k0 + cc;
        if (PRE) {
            *(short8*)&Wl[r * LDW + cc] = *(const short8*)&wsrc[si];
        } else {
            const float* p = fsrc + si;
            float4 f0 = *(const float4*)p;
            float4 f1 = *(const float4*)(p + 4);
            union { ushort u[8]; short8 s; } t;
            t.u[0]=f2bf(f0.x); t.u[1]=f2bf(f0.y); t.u[2]=f2bf(f0.z); t.u[3]=f2bf(f0.w);
            t.u[4]=f2bf(f1.x); t.u[5]=f2bf(f1.y); t.u[6]=f2bf(f1.z); t.u[7]=f2bf(f1.w);
            *(short8*)&Wl[r * LDW + cc] = t.s;
        }
    }
}

__device__ __forceinline__ short8 ldA8(const ushort* p) {   // 8B-aligned LDS
    union { uint2 x[2]; short8 s; } r;
    r.x[0] = *(const uint2*)p;
    r.x[1] = *(const uint2*)(p + 4);
    return r.s;
}

// acc[nt] += A(16 tok x K=128, wave-local LDS) @ Wl(128x128 LDS tile)^T
__device__ __forceinline__ void gemm16(const ushort* A, const ushort* Wl,
                                       int q, int c, f32x4 acc[8]) {
#pragma unroll
    for (int kk = 0; kk < 4; ++kk) {
        short8 b[8];
#pragma unroll
        for (int nt = 0; nt < 8; ++nt)
            b[nt] = *(const short8*)&Wl[(nt * 16 + c) * LDW + kk * 32 + q * 8];
        short8 a = ldA8(A + c * LDA + kk * 32 + q * 8);
#pragma unroll
        for (int nt = 0; nt < 8; ++nt)
            acc[nt] = __builtin_amdgcn_mfma_f32_16x16x32_bf16(a, b[nt], acc[nt], 0, 0, 0);
    }
}

__device__ __forceinline__ void zero8(f32x4 a[8]) {
#pragma unroll
    for (int nt = 0; nt < 8; ++nt) a[nt] = (f32x4){0.f, 0.f, 0.f, 0.f};
}

// per-token LN stats (R5-proven): token = lane&15, partials across 4 quads
__device__ __forceinline__ void ln_stats(const float* t, float& mu, float& rs) {
    float s1 = 0.f, s2 = 0.f;
#pragma unroll
    for (int i = 0; i < 32; ++i) { s1 += t[i]; s2 += t[i] * t[i]; }
    s1 += __shfl_xor(s1, 16); s2 += __shfl_xor(s2, 16);
    s1 += __shfl_xor(s1, 32); s2 += __shfl_xor(s2, 32);
    mu = s1 * (1.f / 128.f);
    rs = rsqrtf(s2 * (1.f / 128.f) - mu * mu + 1e-5f);
}

template<bool PRE>
__global__ __launch_bounds__(512, 1) void rwkv_mfma(
    const float* __restrict__ X,
    const float* __restrict__ G0, const float* __restrict__ B0,
    const float* __restrict__ G1, const float* __restrict__ B1,
    const float* __restrict__ G2, const float* __restrict__ B2,
    const float* __restrict__ WoutF, const float* __restrict__ WwhtF,
    const float* __restrict__ WkeyF, const float* __restrict__ WrecF,
    const float* __restrict__ WvalF,
    const ushort* __restrict__ Wb,
    float* __restrict__ Y)
{
    __shared__ __align__(16) ushort actS[NW * TPW * LDA];   // 33792 B wave-local
    __shared__ __align__(16) ushort whtS[NW * TPW * LDA];   // 33792 B wave-local
    __shared__ __align__(16) ushort WldsA[128 * LDW];       // 34816 B: OUT,KEY*,REC
    __shared__ __align__(16) ushort WldsB[128 * LDW];       // 34816 B: WHT,VAL*
    // total 137216 B -> 1 block/CU; 8 waves/CU = 2 waves/SIMD

    const int tid = threadIdx.x;
    const int w = tid >> 6, l = tid & 63;
    const int q = l >> 4, c = l & 15;
    ushort* act = actS + w * (TPW * LDA);   // a1 / y2 / k-chunk / prod (bf16)
    ushort* wht = whtS + w * (TPW * LDA);   // att temp, then wht (bf16)

    const int s128 = blockIdx.x * 128;         // 128 tokens per block (8 waves x 16)
    const int bb  = s128 >> 14;
    const int s0  = s128 & (HW - 1);           // 16384/128: blocks never cross batch
    const long gbase = (long)(bb * CDIM) * HW + s0 + 16 * w + c;

    // ==== P0: stage OUT -> A (overlaps X loads + LN0/LN1) ====
    stageW<PRE>(WldsA, Wb + OFF_OUT, WoutF, 128, 0, 0, tid);

    float t[32];
#pragma unroll
    for (int i = 0; i < 32; ++i) t[i] = X[gbase + (long)(32 * q + i) * HW];

    float mu, rs;
    ln_stats(t, mu, rs);                       // LN0
#pragma unroll
    for (int i = 0; i < 32; ++i) {
        int ch = 32 * q + i;
        t[i] = (t[i] - mu) * rs * G0[ch] + B0[ch];
    }
    ln_stats(t, mu, rs);                       // LN1 + silu -> act
#pragma unroll
    for (int j = 0; j < 16; ++j) {
        int ch = 32 * q + 2 * j;
        float y0 = (t[2*j]   - mu) * rs * G1[ch]   + B1[ch];
        float y1 = (t[2*j+1] - mu) * rs * G1[ch+1] + B1[ch+1];
        y0 *= sigm(y0); y1 *= sigm(y1);
        *(uint*)&act[c * LDA + ch] = (uint)f2bf(y0) | ((uint)f2bf(y1) << 16);
    }
    __syncthreads();                           // OUT staged, a1 visible

    // ==== P1: att = a1 @ W_out^T (A); stage WHT -> B ====
    stageW<PRE>(WldsB, Wb + OFF_WHT, WwhtF, 128, 0, 0, tid);
    f32x4 acc[8];
    zero8(acc);
    gemm16(act, WldsA, q, c, acc);
#pragma unroll
    for (int nt = 0; nt < 8; ++nt)
#pragma unroll
        for (int r = 0; r < 4; ++r)
            wht[(q * 4 + r) * LDA + nt * 16 + c] = f2bf(acc[nt][r]);
    __syncthreads();                           // WHT staged, att visible, A free

    // ==== P2: t1 = t + att; y2 = LN2(t1); wht = y2 @ W_whiten^T (B);
    //          stage KEY0 -> A ====
    stageW<PRE>(WldsA, Wb + OFF_KEY, WkeyF, 128, 0, 0, tid);
#pragma unroll
    for (int i = 0; i < 32; ++i)
        t[i] += bf2f(wht[c * LDA + 32 * q + i]);    // t1 = t + att
    ln_stats(t, mu, rs);                       // LN2
#pragma unroll
    for (int j = 0; j < 16; ++j) {
        int ch = 32 * q + 2 * j;
        float y0 = (t[2*j]   - mu) * rs * G2[ch]   + B2[ch];
        float y1 = (t[2*j+1] - mu) * rs * G2[ch+1] + B2[ch+1];
        *(uint*)&act[c * LDA + ch] = (uint)f2bf(y0) | ((uint)f2bf(y1) << 16);
    }
    zero8(acc);
    gemm16(act, WldsB, q, c, acc);             // y2 writes precede reads in-wave
#pragma unroll
    for (int nt = 0; nt < 8; ++nt)             // overwrites att (read above, in-wave)
#pragma unroll
        for (int r = 0; r < 4; ++r)
            wht[(q * 4 + r) * LDA + nt * 16 + c] = f2bf(acc[nt][r]);
    __syncthreads();                           // KEY0 staged, wht visible, B free

    // ==== chunks: KEY_c on A (stage VAL_c -> B); VAL_c on B (stage next -> A) ====
    f32x4 akv[8];
    zero8(akv);
    for (int chunk = 0; chunk < 4; ++chunk) {
        // KEY phase: k = relu(wht @ W_key_c^T)^2
        stageW<PRE>(WldsB, Wb + OFF_VAL, WvalF, 512, 0, chunk * 128, tid);
        zero8(acc);
        gemm16(wht, WldsA, q, c, acc);
#pragma unroll
        for (int nt = 0; nt < 8; ++nt)
#pragma unroll
            for (int r = 0; r < 4; ++r) {
                float v = fmaxf(acc[nt][r], 0.f);
                act[(q * 4 + r) * LDA + nt * 16 + c] = f2bf(v * v);
            }
        __syncthreads();                       // VAL_c staged, k visible, A free

        // VAL phase: akv += k @ W_value_c^T
        if (chunk < 3)
            stageW<PRE>(WldsA, Wb + OFF_KEY, WkeyF, 128, (chunk + 1) * 128, 0, tid);
        else
            stageW<PRE>(WldsA, Wb + OFF_REC, WrecF, 128, 0, 0, tid);
        gemm16(act, WldsB, q, c, akv);
        __syncthreads();                       // next tile staged, B free
    }

    // ==== P11: r = sigmoid(wht @ W_recep^T) (A); prod = r*kv -> act ====
    zero8(acc);
    gemm16(wht, WldsA, q, c, acc);
#pragma unroll
    for (int nt = 0; nt < 8; ++nt)
#pragma unroll
        for (int r = 0; r < 4; ++r)
            act[(q * 4 + r) * LDA + nt * 16 + c] =
                f2bf(sigm(acc[nt][r]) * akv[nt][r]);
    __syncthreads();                           // prod visible

    // ==== out = 2 * (t1 + r*kv) ====
#pragma unroll
    for (int i = 0; i < 32; ++i) {
        float t2 = t[i] + bf2f(act[c * LDA + 32 * q + i]);
        Y[gbase + (long)(32 * q + i) * HW] = 2.f * t2;
    }
}

extern "C" void kernel_launch(void* const* d_in, const int* in_sizes, int n_in,
                              void* d_out, int out_size, void* d_ws, size_t ws_size,
                              hipStream_t stream) {
    (void)in_sizes; (void)n_in; (void)out_size;
    const float* X  = (const float*)d_in[0];
    const float* G0 = (const float*)d_in[1];  const float* B0 = (const float*)d_in[2];
    const float* G1 = (const float*)d_in[3];  const float* B1 = (const float*)d_in[4];
    const float* G2 = (const float*)d_in[5];  const float* B2 = (const float*)d_in[6];
    const float* Wout = (const float*)d_in[7];
    const float* Wwht = (const float*)d_in[8];
    const float* Wkey = (const float*)d_in[9];
    const float* Wrec = (const float*)d_in[10];
    const float* Wval = (const float*)d_in[11];
    float* Y = (float*)d_out;

    const bool pre = ws_size >= (size_t)WS_ELEMS * 2;
    if (pre) {
        ushort* ws = (ushort*)d_ws;
        cvt_all<<<704, 256, 0, stream>>>(Wout, Wwht, Wkey, Wrec, Wval, ws);
        rwkv_mfma<true><<<512, 512, 0, stream>>>(
            X, G0, B0, G1, B1, G2, B2,
            Wout, Wwht, Wkey, Wrec, Wval, ws, Y);
    } else {
        rwkv_mfma<false><<<512, 512, 0, stream>>>(
            X, G0, B0, G1, B1, G2, B2,
            Wout, Wwht, Wkey, Wrec, Wval, nullptr, Y);
    }
}

// Round 6
// 159.300 us; speedup vs baseline: 1.1541x; 1.0037x over previous
//
#include <hip/hip_runtime.h>

// HSI_RWKV fused block kernel, MI355X (gfx950), R14.
// out = block(x) + T(block(T(x))) == 2 * block_per_token(x)  (block is per-token).
// R14 = R13's PROVEN structure (8 waves/block, 512 thr, grid 512, dbuf
// WldsA/WldsB, padded LDA/LDW, register staging, linear cvt_all, identical
// barrier skeleton) + exactly ONE semantic change:
//   wa[4] A-FRAGMENT CAPTURE: after the whiten-D transpose store into wht,
//   each lane reads its 4 MFMA A-fragments (the same bf16 bits KEY/REC gemms
//   would re-read from LDS) once into registers; KEY x4 and REC gemms use
//   gemm16r(wa,...). Bit-identical math; saves 20 ds_reads/wave + lgkmcnt
//   deps. +16 VGPR (116 -> ~132), NO launch_bounds cap -> no spill (the
//   R9/R10 failures are attributed to __launch_bounds__(256,3) forcing a
//   spill under graph capture; this probe tests wa[] with that suspect
//   removed). Also drops the final pre-output barrier (act is wave-local).
// If this FAILS: wa[]/gemm16r is definitively guilty (only change) ->
// permanent quarantine. If it passes: unlocks single-act-buffer NW=16 next.
// MFMA layouts (m89/m91): A m=lane&15,k=q*8+j; B n=lane&15,k=q*8+j;
// D row(token)=q*4+reg, col(out-ch)=lane&15. Frags: short8 bit patterns.

#define HW    16384
#define CDIM  128
#define LDA   132     // act/wht row stride (ushorts); 264 B, 8B-aligned
#define LDW   136     // weight tile row stride (ushorts); 272 B -> ~2-way banks
#define TPW   16      // tokens per wave
#define NW    8       // waves per block (512 threads)

#define OFF_OUT 0
#define OFF_WHT 16384
#define OFF_KEY 32768
#define OFF_REC 98304
#define OFF_VAL 114688
#define WS_ELEMS 180224   // *2 bytes

typedef __attribute__((ext_vector_type(8))) short short8;  // 8 bf16 bit patterns
typedef __attribute__((ext_vector_type(4))) float f32x4;

__device__ __forceinline__ float bf2f(ushort h) {
    union { uint u; float f; } v; v.u = ((uint)h) << 16; return v.f;
}
__device__ __forceinline__ ushort f2bf(float f) {
    union { float f; uint u; } v; v.f = f;
    uint u = v.u + 0x7fffu + ((v.u >> 16) & 1u);   // RNE
    return (ushort)(u >> 16);
}
__device__ __forceinline__ float sigm(float x) {
    return 1.f / (1.f + __expf(-x));
}

// one-launch weight conversion: 180224 elements, grid 704 x 256 (R7+-proven)
__global__ void cvt_all(const float* __restrict__ Wout, const float* __restrict__ Wwht,
                        const float* __restrict__ Wkey, const float* __restrict__ Wrec,
                        const float* __restrict__ Wval, ushort* __restrict__ ws) {
    int i = blockIdx.x * 256 + threadIdx.x;
    float v;
    if      (i < 32768)  v = (i < 16384) ? Wout[i] : Wwht[i - 16384];
    else if (i < 98304)  v = Wkey[i - 32768];
    else if (i < 114688) v = Wrec[i - 98304];
    else                 v = Wval[i - 114688];
    ws[i] = f2bf(v);
}

// Stage a 128x128 bf16 tile W[row0..row0+128)[k0..k0+128) into Wl (LDW-padded).
// 512 threads x 16B x 4 iters = 32 KB; batched independent loads.
template<bool PRE>
__device__ __forceinline__ void stageW(ushort* Wl,
                                       const ushort* __restrict__ wsrc,
                                       const float* __restrict__ fsrc,
                                       int src_ld, int row0, int k0, int tid) {
    const int rr = tid >> 4, cc = (tid & 15) * 8;   // rr in 0..31
#pragma unroll
    for (int j = 0; j < 4; ++j) {
        const int r  = j * 32 + rr;
        const int si = (row0 + r) * src_ld + k0 + cc;
        if (PRE) {
            *(short8*)&Wl[r * LDW + cc] = *(const short8*)&wsrc[si];
        } else {
            const float* p = fsrc + si;
            float4 f0 = *(const float4*)p;
            float4 f1 = *(const float4*)(p + 4);
            union { ushort u[8]; short8 s; } t;
            t.u[0]=f2bf(f0.x); t.u[1]=f2bf(f0.y); t.u[2]=f2bf(f0.z); t.u[3]=f2bf(f0.w);
            t.u[4]=f2bf(f1.x); t.u[5]=f2bf(f1.y); t.u[6]=f2bf(f1.z); t.u[7]=f2bf(f1.w);
            *(short8*)&Wl[r * LDW + cc] = t.s;
        }
    }
}

__device__ __forceinline__ short8 ldA8(const ushort* p) {   // 8B-aligned LDS
    union { uint2 x[2]; short8 s; } r;
    r.x[0] = *(const uint2*)p;
    r.x[1] = *(const uint2*)(p + 4);
    return r.s;
}

// acc[nt] += A(16 tok x K=128, wave-local LDS) @ Wl(128x128 LDS tile)^T
__device__ __forceinline__ void gemm16(const ushort* A, const ushort* Wl,
                                       int q, int c, f32x4 acc[8]) {
#pragma unroll
    for (int kk = 0; kk < 4; ++kk) {
        short8 b[8];
#pragma unroll
        for (int nt = 0; nt < 8; ++nt)
            b[nt] = *(const short8*)&Wl[(nt * 16 + c) * LDW + kk * 32 + q * 8];
        short8 a = ldA8(A + c * LDA + kk * 32 + q * 8);
#pragma unroll
        for (int nt = 0; nt < 8; ++nt)
            acc[nt] = __builtin_amdgcn_mfma_f32_16x16x32_bf16(a, b[nt], acc[nt], 0, 0, 0);
    }
}

// same, but A-fragments come from registers (wa[] -- whitened activations)
__device__ __forceinline__ void gemm16r(const short8* wa, const ushort* Wl,
                                        int q, int c, f32x4 acc[8]) {
#pragma unroll
    for (int kk = 0; kk < 4; ++kk) {
        short8 b[8];
#pragma unroll
        for (int nt = 0; nt < 8; ++nt)
            b[nt] = *(const short8*)&Wl[(nt * 16 + c) * LDW + kk * 32 + q * 8];
#pragma unroll
        for (int nt = 0; nt < 8; ++nt)
            acc[nt] = __builtin_amdgcn_mfma_f32_16x16x32_bf16(wa[kk], b[nt], acc[nt], 0, 0, 0);
    }
}

__device__ __forceinline__ void zero8(f32x4 a[8]) {
#pragma unroll
    for (int nt = 0; nt < 8; ++nt) a[nt] = (f32x4){0.f, 0.f, 0.f, 0.f};
}

// per-token LN stats (R5-proven): token = lane&15, partials across 4 quads
__device__ __forceinline__ void ln_stats(const float* t, float& mu, float& rs) {
    float s1 = 0.f, s2 = 0.f;
#pragma unroll
    for (int i = 0; i < 32; ++i) { s1 += t[i]; s2 += t[i] * t[i]; }
    s1 += __shfl_xor(s1, 16); s2 += __shfl_xor(s2, 16);
    s1 += __shfl_xor(s1, 32); s2 += __shfl_xor(s2, 32);
    mu = s1 * (1.f / 128.f);
    rs = rsqrtf(s2 * (1.f / 128.f) - mu * mu + 1e-5f);
}

template<bool PRE>
__global__ __launch_bounds__(512, 1) void rwkv_mfma(
    const float* __restrict__ X,
    const float* __restrict__ G0, const float* __restrict__ B0,
    const float* __restrict__ G1, const float* __restrict__ B1,
    const float* __restrict__ G2, const float* __restrict__ B2,
    const float* __restrict__ WoutF, const float* __restrict__ WwhtF,
    const float* __restrict__ WkeyF, const float* __restrict__ WrecF,
    const float* __restrict__ WvalF,
    const ushort* __restrict__ Wb,
    float* __restrict__ Y)
{
    __shared__ __align__(16) ushort actS[NW * TPW * LDA];   // 33792 B wave-local
    __shared__ __align__(16) ushort whtS[NW * TPW * LDA];   // 33792 B wave-local
    __shared__ __align__(16) ushort WldsA[128 * LDW];       // 34816 B: OUT,KEY*,REC
    __shared__ __align__(16) ushort WldsB[128 * LDW];       // 34816 B: WHT,VAL*
    // total 137216 B -> 1 block/CU; 8 waves/CU = 2 waves/SIMD

    const int tid = threadIdx.x;
    const int w = tid >> 6, l = tid & 63;
    const int q = l >> 4, c = l & 15;
    ushort* act = actS + w * (TPW * LDA);   // a1 / y2 / k-chunk / prod (bf16)
    ushort* wht = whtS + w * (TPW * LDA);   // att temp, then wht (bf16)

    const int s128 = blockIdx.x * 128;         // 128 tokens per block (8 waves x 16)
    const int bb  = s128 >> 14;
    const int s0  = s128 & (HW - 1);           // 16384%128==0: blocks never cross batch
    const long gbase = (long)(bb * CDIM) * HW + s0 + 16 * w + c;

    // ==== P0: stage OUT -> A (overlaps X loads + LN0/LN1) ====
    stageW<PRE>(WldsA, Wb + OFF_OUT, WoutF, 128, 0, 0, tid);

    float t[32];
#pragma unroll
    for (int i = 0; i < 32; ++i) t[i] = X[gbase + (long)(32 * q + i) * HW];

    float mu, rs;
    ln_stats(t, mu, rs);                       // LN0
#pragma unroll
    for (int i = 0; i < 32; ++i) {
        int ch = 32 * q + i;
        t[i] = (t[i] - mu) * rs * G0[ch] + B0[ch];
    }
    ln_stats(t, mu, rs);                       // LN1 + silu -> act
#pragma unroll
    for (int j = 0; j < 16; ++j) {
        int ch = 32 * q + 2 * j;
        float y0 = (t[2*j]   - mu) * rs * G1[ch]   + B1[ch];
        float y1 = (t[2*j+1] - mu) * rs * G1[ch+1] + B1[ch+1];
        y0 *= sigm(y0); y1 *= sigm(y1);
        *(uint*)&act[c * LDA + ch] = (uint)f2bf(y0) | ((uint)f2bf(y1) << 16);
    }
    __syncthreads();                           // OUT staged, a1 visible

    // ==== P1: att = a1 @ W_out^T (A); stage WHT -> B ====
    stageW<PRE>(WldsB, Wb + OFF_WHT, WwhtF, 128, 0, 0, tid);
    f32x4 acc[8];
    zero8(acc);
    gemm16(act, WldsA, q, c, acc);
#pragma unroll
    for (int nt = 0; nt < 8; ++nt)
#pragma unroll
        for (int r = 0; r < 4; ++r)
            wht[(q * 4 + r) * LDA + nt * 16 + c] = f2bf(acc[nt][r]);
    __syncthreads();                           // WHT staged, att visible, A free

    // ==== P2: t1 = t + att; y2 = LN2(t1); wht = y2 @ W_whiten^T (B);
    //          stage KEY0 -> A; capture wa[] ====
    stageW<PRE>(WldsA, Wb + OFF_KEY, WkeyF, 128, 0, 0, tid);
#pragma unroll
    for (int i = 0; i < 32; ++i)
        t[i] += bf2f(wht[c * LDA + 32 * q + i]);    // t1 = t + att
    ln_stats(t, mu, rs);                       // LN2
#pragma unroll
    for (int j = 0; j < 16; ++j) {
        int ch = 32 * q + 2 * j;
        float y0 = (t[2*j]   - mu) * rs * G2[ch]   + B2[ch];
        float y1 = (t[2*j+1] - mu) * rs * G2[ch+1] + B2[ch+1];
        *(uint*)&act[c * LDA + ch] = (uint)f2bf(y0) | ((uint)f2bf(y1) << 16);
    }
    zero8(acc);
    gemm16(act, WldsB, q, c, acc);             // y2 writes precede reads in-wave
#pragma unroll
    for (int nt = 0; nt < 8; ++nt)             // overwrites att (read above, in-wave)
#pragma unroll
        for (int r = 0; r < 4; ++r)
            wht[(q * 4 + r) * LDA + nt * 16 + c] = f2bf(acc[nt][r]);
    // capture A-frags from wht: same bf16 bits the KEY/REC gemms would re-read.
    // In-wave DS ordering: the ds_writes above issue before these ds_reads.
    short8 wa[4];
#pragma unroll
    for (int kk = 0; kk < 4; ++kk)
        wa[kk] = ldA8(wht + c * LDA + kk * 32 + q * 8);
    __syncthreads();                           // KEY0 staged, B free

    // ==== chunks: KEY_c on A (stage VAL_c -> B); VAL_c on B (stage next -> A) ====
    f32x4 akv[8];
    zero8(akv);
    for (int chunk = 0; chunk < 4; ++chunk) {
        // KEY phase: k = relu(wa @ W_key_c^T)^2
        stageW<PRE>(WldsB, Wb + OFF_VAL, WvalF, 512, 0, chunk * 128, tid);
        zero8(acc);
        gemm16r(wa, WldsA, q, c, acc);
#pragma unroll
        for (int nt = 0; nt < 8; ++nt)
#pragma unroll
            for (int r = 0; r < 4; ++r) {
                float v = fmaxf(acc[nt][r], 0.f);
                act[(q * 4 + r) * LDA + nt * 16 + c] = f2bf(v * v);
            }
        __syncthreads();                       // VAL_c staged, k visible, A free

        // VAL phase: akv += k @ W_value_c^T
        if (chunk < 3)
            stageW<PRE>(WldsA, Wb + OFF_KEY, WkeyF, 128, (chunk + 1) * 128, 0, tid);
        else
            stageW<PRE>(WldsA, Wb + OFF_REC, WrecF, 128, 0, 0, tid);
        gemm16(act, WldsB, q, c, akv);
        __syncthreads();                       // next tile staged, B free
    }

    // ==== P11: r = sigmoid(wa @ W_recep^T) (A); prod = r*kv -> act ====
    zero8(acc);
    gemm16r(wa, WldsA, q, c, acc);
#pragma unroll
    for (int nt = 0; nt < 8; ++nt)
#pragma unroll
        for (int r = 0; r < 4; ++r)
            act[(q * 4 + r) * LDA + nt * 16 + c] =
                f2bf(sigm(acc[nt][r]) * akv[nt][r]);
    // no barrier: act is wave-local and DS ops within a wave are in-order;
    // the out-loop reads below are issued after the prod writes above.

    // ==== out = 2 * (t1 + r*kv) ====
#pragma unroll
    for (int i = 0; i < 32; ++i) {
        float t2 = t[i] + bf2f(act[c * LDA + 32 * q + i]);
        Y[gbase + (long)(32 * q + i) * HW] = 2.f * t2;
    }
}

extern "C" void kernel_launch(void* const* d_in, const int* in_sizes, int n_in,
                              void* d_out, int out_size, void* d_ws, size_t ws_size,
                              hipStream_t stream) {
    (void)in_sizes; (void)n_in; (void)out_size;
    const float* X  = (const float*)d_in[0];
    const float* G0 = (const float*)d_in[1];  const float* B0 = (const float*)d_in[2];
    const float* G1 = (const float*)d_in[3];  const float* B1 = (const float*)d_in[4];
    const float* G2 = (const float*)d_in[5];  const float* B2 = (const float*)d_in[6];
    const float* Wout = (const float*)d_in[7];
    const float* Wwht = (const float*)d_in[8];
    const float* Wkey = (const float*)d_in[9];
    const float* Wrec = (const float*)d_in[10];
    const float* Wval = (const float*)d_in[11];
    float* Y = (float*)d_out;

    const bool pre = ws_size >= (size_t)WS_ELEMS * 2;
    if (pre) {
        ushort* ws = (ushort*)d_ws;
        cvt_all<<<704, 256, 0, stream>>>(Wout, Wwht, Wkey, Wrec, Wval, ws);
        rwkv_mfma<true><<<512, 512, 0, stream>>>(
            X, G0, B0, G1, B1, G2, B2,
            Wout, Wwht, Wkey, Wrec, Wval, ws, Y);
    } else {
        rwkv_mfma<false><<<512, 512, 0, stream>>>(
            X, G0, B0, G1, B1, G2, B2,
            Wout, Wwht, Wkey, Wrec, Wval, nullptr, Y);
    }
}